// Round 2
// baseline (672.786 us; speedup 1.0000x reference)
//
#include <hip/hip_runtime.h>
#include <math.h>

#define B_   16
#define C_   512
#define N_   1681
#define Np   1792      // padded N (multiple of 128)
#define CK_  256
#define EPSV 1e-5f
#define SCALE 0.0625f  // Ck^-0.5

typedef __bf16 bf16x8 __attribute__((ext_vector_type(8)));
typedef __bf16 bf16x4 __attribute__((ext_vector_type(4)));
typedef float  f32x4  __attribute__((ext_vector_type(4)));

// ---------------------------------------------------------------------------
// XCD-aware bijective swizzle: raw blockIdx round-robins over 8 XCDs; remap
// so each XCD owns a contiguous chunk of logical work ids.  q = nwg/8.
// ---------------------------------------------------------------------------
__device__ __forceinline__ int xcd_swz(int orig, int q)
{
    return (orig & 7) * q + (orig >> 3);
}

// ---------------------------------------------------------------------------
// Stage a 128-row x 64-bf16 (128 B) tile global->LDS via async 16B loads.
// LDS chunk (row, col) holds global chunk (row, col ^ (row&7))  [xor swizzle]
// ---------------------------------------------------------------------------
__device__ __forceinline__
void stage_tile(const char* gbase, int ld_bytes, char* lds, int w, int lane)
{
    #pragma unroll
    for (int i = 0; i < 4; ++i) {
        int chunk = (i * 4 + w) * 64 + lane;       // 0..1023
        int row   = chunk >> 3;                    // 8 chunks (128B) per row
        int col   = chunk & 7;
        int scol  = col ^ (row & 7);
        const char* g = gbase + (size_t)row * ld_bytes + scol * 16;
        char* l = lds + (size_t)(i * 4 + w) * 1024;  // wave-uniform base
        __builtin_amdgcn_global_load_lds(
            (const __attribute__((address_space(1))) void*)g,
            (__attribute__((address_space(3))) void*)l, 16, 0, 0);
    }
}

// ---------------------------------------------------------------------------
// 128x128 tile MFMA core: As/Bs are [128 rows][64 k] bf16, xor-swizzled.
// Wave w (0..3): wr=w>>1 selects A-row half, wc=w&1 selects B-row half.
// ---------------------------------------------------------------------------
__device__ __forceinline__
void mma_tile(const __bf16* As, const __bf16* Bs, f32x4 acc[4][4], int wr, int wc, int lane)
{
    const int l15 = lane & 15, quad = lane >> 4;
    #pragma unroll
    for (int kk = 0; kk < 2; ++kk) {
        bf16x8 af[4], bfr[4];
        #pragma unroll
        for (int i = 0; i < 4; ++i) {
            int row = wr * 64 + i * 16 + l15;
            int c   = (kk * 4 + quad) ^ (row & 7);
            af[i] = *(const bf16x8*)(As + row * 64 + c * 8);
        }
        #pragma unroll
        for (int j = 0; j < 4; ++j) {
            int row = wc * 64 + j * 16 + l15;
            int c   = (kk * 4 + quad) ^ (row & 7);
            bfr[j] = *(const bf16x8*)(Bs + row * 64 + c * 8);
        }
        #pragma unroll
        for (int i = 0; i < 4; ++i)
            #pragma unroll
            for (int j = 0; j < 4; ++j)
                acc[i][j] = __builtin_amdgcn_mfma_f32_16x16x32_bf16(
                    af[i], bfr[j], acc[i][j], 0, 0, 0);
    }
}

// ---------------------------------------------------------------------------
// 2-phase pipelined K-loop (guide §5.5 T3 minimum recipe):
//   prologue: STAGE(buf0, t=0); vmcnt(0); barrier;
//   iter t:   STAGE(buf^1, t+1);  mma(buf);  vmcnt(0); barrier;
// Next-tile load latency hides under current-tile ds_read+MFMA.
// ---------------------------------------------------------------------------
#define PIPELINED_GEMM(Abase, lda, Bbase, ldb, NT)                              \
    stage_tile(Abase, lda, (char*)As[0], w, lane);                              \
    stage_tile(Bbase, ldb, (char*)Bs[0], w, lane);                              \
    asm volatile("s_waitcnt vmcnt(0)" ::: "memory");                            \
    __builtin_amdgcn_s_barrier();                                               \
    {                                                                           \
        int cur = 0;                                                            \
        for (int kt = 0; kt < (NT); ++kt) {                                     \
            if (kt + 1 < (NT)) {                                                \
                stage_tile((Abase) + (kt + 1) * 128, lda, (char*)As[cur ^ 1], w, lane); \
                stage_tile((Bbase) + (kt + 1) * 128, ldb, (char*)Bs[cur ^ 1], w, lane); \
            }                                                                   \
            mma_tile(As[cur], Bs[cur], acc, w >> 1, w & 1, lane);               \
            if (kt + 1 < (NT)) {                                                \
                asm volatile("s_waitcnt vmcnt(0)" ::: "memory");                \
                __builtin_amdgcn_s_barrier();                                   \
            }                                                                   \
            cur ^= 1;                                                           \
        }                                                                       \
    }

// ---------------------------------------------------------------------------
// cvt_w: Wh[512][512] bf16 = [Wq; Wk], b2[512] f32 = [bq; bk]
// ---------------------------------------------------------------------------
__global__ __launch_bounds__(256)
void cvt_w_kernel(const float* __restrict__ Wq, const float* __restrict__ Wk,
                  const float* __restrict__ bq, const float* __restrict__ bk,
                  __bf16* __restrict__ Wh, float* __restrict__ b2)
{
    int idx = blockIdx.x * 1024 + threadIdx.x * 4;
    #pragma unroll
    for (int p = 0; p < 4; ++p) {
        int e = idx + p;
        int row = e >> 9, col = e & 511;
        float v = (row < 256) ? Wq[row * 512 + col] : Wk[(row - 256) * 512 + col];
        Wh[e] = (__bf16)v;
    }
    if (blockIdx.x == 0) {
        int t = threadIdx.x;
        b2[t]       = bq[t];
        b2[256 + t] = bk[t];
    }
}

// ---------------------------------------------------------------------------
// cvt_x: xh[b][c][n<Np] bf16 (zero pad), xt[b][n<Np][c] bf16 (zero pad rows)
// ---------------------------------------------------------------------------
__global__ __launch_bounds__(256)
void cvt_x_kernel(const float* __restrict__ x,
                  __bf16* __restrict__ xh, __bf16* __restrict__ xt)
{
    __shared__ float tile[32][33];
    const int t = threadIdx.x;
    const int n0 = blockIdx.x * 32, c0 = blockIdx.y * 32, b = blockIdx.z;
    const float* xb = x + (size_t)b * C_ * N_;
    #pragma unroll
    for (int p = 0; p < 4; ++p) {
        int lin = p * 256 + t;
        int i = lin >> 5, j = lin & 31;     // i: c-offset, j: n-offset
        int n = n0 + j;
        float v = (n < N_) ? xb[(size_t)(c0 + i) * N_ + n] : 0.0f;
        tile[i][j] = v;
        xh[(size_t)b * C_ * Np + (size_t)(c0 + i) * Np + n] = (__bf16)v;
    }
    __syncthreads();
    #pragma unroll
    for (int p = 0; p < 4; ++p) {
        int lin = p * 256 + t;
        int i = lin >> 5, j = lin & 31;     // i: n-offset, j: c-offset
        xt[(size_t)b * Np * C_ + (size_t)(n0 + i) * C_ + (c0 + j)] = (__bf16)tile[j][i];
    }
}

// ---------------------------------------------------------------------------
// proj: QKt[b][n][k2] = sum_c xt[b][n][c] * Wh[k2][c] + b2[k2]
// 1D grid 896: k2t fastest (consecutive blocks share the xt A-panel)
// ---------------------------------------------------------------------------
__global__ __launch_bounds__(256)
void proj_kernel(const __bf16* __restrict__ xt, const __bf16* __restrict__ Wh,
                 const float* __restrict__ b2, __bf16* __restrict__ QKt)
{
    __shared__ __bf16 As[2][128 * 64];
    __shared__ __bf16 Bs[2][128 * 64];
    const int t = threadIdx.x, w = t >> 6, lane = t & 63;
    const int wg = xcd_swz(blockIdx.x, 112);       // 896/8
    const int k20 = (wg & 3) * 128;
    const int n0  = ((wg >> 2) % 14) * 128;
    const int b   = wg / 56;
    const char* Abase = (const char*)xt + ((size_t)b * Np + n0) * (C_ * 2);
    const char* Bbase = (const char*)Wh + (size_t)k20 * (C_ * 2);

    f32x4 acc[4][4] = {};
    PIPELINED_GEMM(Abase, C_ * 2, Bbase, C_ * 2, C_ / 64)

    const int l15 = lane & 15, quad = lane >> 4;
    __bf16* ob = QKt + (size_t)b * Np * 512;
    #pragma unroll
    for (int j = 0; j < 4; ++j) {
        int k2 = k20 + (w & 1) * 64 + j * 16 + l15;
        float bias = b2[k2];
        #pragma unroll
        for (int i = 0; i < 4; ++i)
            #pragma unroll
            for (int r = 0; r < 4; ++r) {
                int n = n0 + (w >> 1) * 64 + i * 16 + quad * 4 + r;
                ob[(size_t)n * 512 + k2] = (__bf16)(acc[i][j][r] + bias);
            }
    }
}

// ---------------------------------------------------------------------------
// sim: S[b][n][m] = SCALE * sum_k Qt[n][k] * Kt[m][k]
// 1D grid 3136: mt fastest (consecutive blocks share the Qt A-panel);
// 2 batches of QKt (3.7 MB) fit one XCD's 4 MB L2 after the swizzle.
// ---------------------------------------------------------------------------
__global__ __launch_bounds__(256)
void sim_kernel(const __bf16* __restrict__ QKt, __bf16* __restrict__ S)
{
    __shared__ __bf16 As[2][128 * 64];
    __shared__ __bf16 Bs[2][128 * 64];
    const int t = threadIdx.x, w = t >> 6, lane = t & 63;
    const int wg = xcd_swz(blockIdx.x, 392);       // 3136/8
    const int m0 = (wg % 14) * 128;
    const int n0 = ((wg / 14) % 14) * 128;
    const int b  = wg / 196;
    const char* base = (const char*)QKt + (size_t)b * Np * 1024;
    const char* Abase = base + (size_t)n0 * 1024;          // Qt rows
    const char* Bbase = base + (size_t)m0 * 1024 + 512;    // Kt rows (+256 elems)

    f32x4 acc[4][4] = {};
    PIPELINED_GEMM(Abase, 1024, Bbase, 1024, CK_ / 64)

    const int l15 = lane & 15, quad = lane >> 4;
    __bf16* Sb = S + (size_t)b * Np * Np;
    #pragma unroll
    for (int i = 0; i < 4; ++i)
        #pragma unroll
        for (int r = 0; r < 4; ++r) {
            int n = n0 + (w >> 1) * 64 + i * 16 + quad * 4 + r;
            #pragma unroll
            for (int j = 0; j < 4; ++j) {
                int m = m0 + (w & 1) * 64 + j * 16 + l15;
                Sb[(size_t)n * Np + m] = (__bf16)(acc[i][j][r] * SCALE);
            }
        }
}

// ---------------------------------------------------------------------------
// norm: one WAVE per row, register-resident, vectorized, no LDS/barriers.
// Single sweep: min(s*f), A=sum(s*f^2), F=sum(f); sum_x1 = A - min*F.
// ---------------------------------------------------------------------------
__global__ __launch_bounds__(256, 4)
void norm_kernel(const float* __restrict__ fg, const float* __restrict__ bg,
                 __bf16* __restrict__ S)
{
    const int t = threadIdx.x;
    const int wid = t >> 6, lane = t & 63;
    const int n = blockIdx.x * 4 + wid;
    const int b = blockIdx.y;
    if (n >= N_) return;

    __bf16* Srow = S + (size_t)b * Np * Np + (size_t)n * Np;
    const float* fgrow = fg + ((size_t)b * N_ + n) * N_;
    const float* bgrow = bg + ((size_t)b * N_ + n) * N_;

    float sv[7][4];   // s * f
    float fv[7][4];   // f
    float lmin = INFINITY, aSum = 0.0f, fSum = 0.0f;

    #pragma unroll
    for (int i = 0; i < 7; ++i) {
        const int m0 = i * 256 + lane * 4;
        bf16x4 sr = *(const bf16x4*)(Srow + m0);       // 8B, in-bounds (padded)
        f32x4 f;
        if (m0 + 4 <= N_) {
            f = *(const f32x4*)(fgrow + m0);           // 16B vector load
        } else {
            f[0] = (m0 + 0 < N_) ? fgrow[m0 + 0] : 0.0f;
            f[1] = (m0 + 1 < N_) ? fgrow[m0 + 1] : 0.0f;
            f[2] = (m0 + 2 < N_) ? fgrow[m0 + 2] : 0.0f;
            f[3] = (m0 + 3 < N_) ? fgrow[m0 + 3] : 0.0f;
        }
        #pragma unroll
        for (int k = 0; k < 4; ++k) {
            const bool valid = (m0 + k) < N_;
            const float fk = f[k];
            const float svk = (float)sr[k] * fk;
            sv[i][k] = svk;
            fv[i][k] = fk;
            aSum += svk * fk;
            fSum += fk;
            lmin = fminf(lmin, valid ? svk : INFINITY);
        }
    }

    #pragma unroll
    for (int off = 1; off < 64; off <<= 1) {
        lmin = fminf(lmin, __shfl_xor(lmin, off, 64));
        aSum += __shfl_xor(aSum, off, 64);
        fSum += __shfl_xor(fSum, off, 64);
    }
    const float inv = 1.0f / ((aSum - lmin * fSum) + EPSV);

    #pragma unroll
    for (int i = 0; i < 7; ++i) {
        const int m0 = i * 256 + lane * 4;
        f32x4 g;
        if (m0 + 4 <= N_) {
            g = *(const f32x4*)(bgrow + m0);
        } else {
            g[0] = (m0 + 0 < N_) ? bgrow[m0 + 0] : 0.0f;
            g[1] = (m0 + 1 < N_) ? bgrow[m0 + 1] : 0.0f;
            g[2] = (m0 + 2 < N_) ? bgrow[m0 + 2] : 0.0f;
            g[3] = (m0 + 3 < N_) ? bgrow[m0 + 3] : 0.0f;
        }
        bf16x4 o;
        #pragma unroll
        for (int k = 0; k < 4; ++k) {
            const bool valid = (m0 + k) < N_;
            const float x1 = (sv[i][k] - lmin) * fv[i][k];
            o[k] = (__bf16)(valid ? (x1 * inv + g[k]) : 0.0f);
        }
        *(bf16x4*)(Srow + m0) = o;                     // 8B store, covers pad
    }
}

// ---------------------------------------------------------------------------
// ctx: out[b][c][n] = gamma * sum_m xh[c][m] * A'[n][m] + x[b][c][n]
// 1D grid 896: ct fastest (consecutive blocks share the S B-panel)
// ---------------------------------------------------------------------------
__global__ __launch_bounds__(256)
void ctx_kernel(const __bf16* __restrict__ xh, const __bf16* __restrict__ Ap,
                const float* __restrict__ x, const float* __restrict__ gamma,
                float* __restrict__ out)
{
    __shared__ __bf16 As[2][128 * 64];
    __shared__ __bf16 Bs[2][128 * 64];
    const int t = threadIdx.x, w = t >> 6, lane = t & 63;
    const int wg = xcd_swz(blockIdx.x, 112);       // 896/8
    const int c0 = (wg & 3) * 128;
    const int n0 = ((wg >> 2) % 14) * 128;
    const int b  = wg / 56;
    const char* Abase = (const char*)xh + ((size_t)b * C_ + c0) * (Np * 2);
    const char* Bbase = (const char*)Ap + ((size_t)b * Np + n0) * (Np * 2);

    f32x4 acc[4][4] = {};
    PIPELINED_GEMM(Abase, Np * 2, Bbase, Np * 2, Np / 64)

    const int l15 = lane & 15, quad = lane >> 4;
    const float g = gamma[0];
    const float* xb = x + (size_t)b * C_ * N_;
    float* ob = out + (size_t)b * C_ * N_;
    #pragma unroll
    for (int i = 0; i < 4; ++i)
        #pragma unroll
        for (int r = 0; r < 4; ++r) {
            int c = c0 + (w >> 1) * 64 + i * 16 + quad * 4 + r;
            #pragma unroll
            for (int j = 0; j < 4; ++j) {
                int n = n0 + (w & 1) * 64 + j * 16 + l15;
                if (n < N_) {
                    size_t idx = (size_t)c * N_ + n;
                    ob[idx] = g * acc[i][j][r] + xb[idx];
                }
            }
        }
}

// ---------------------------------------------------------------------------
extern "C" void kernel_launch(void* const* d_in, const int* in_sizes, int n_in,
                              void* d_out, int out_size, void* d_ws, size_t ws_size,
                              hipStream_t stream)
{
    const float* x     = (const float*)d_in[0];
    const float* fg    = (const float*)d_in[1];
    const float* bg    = (const float*)d_in[2];
    const float* Wq    = (const float*)d_in[3];
    const float* bq    = (const float*)d_in[4];
    const float* Wk    = (const float*)d_in[5];
    const float* bk    = (const float*)d_in[6];
    const float* gamma = (const float*)d_in[7];
    float* out = (float*)d_out;

    char* p = (char*)d_ws;
    __bf16* xh  = (__bf16*)p; p += (size_t)B_ * C_ * Np * 2;   // 29.4 MB
    __bf16* xt  = (__bf16*)p; p += (size_t)B_ * Np * C_ * 2;   // 29.4 MB
    __bf16* QKt = (__bf16*)p; p += (size_t)B_ * Np * 512 * 2;  // 29.4 MB
    __bf16* S   = (__bf16*)p; p += (size_t)B_ * Np * Np * 2;   // 102.8 MB
    __bf16* Wh  = (__bf16*)p; p += (size_t)512 * 512 * 2;      // 0.5 MB
    float*  b2  = (float*)p;                                   // 2 KB

    cvt_w_kernel<<<dim3(256), dim3(256), 0, stream>>>(Wq, Wk, bq, bk, Wh, b2);
    cvt_x_kernel<<<dim3(Np / 32, C_ / 32, B_), dim3(256), 0, stream>>>(x, xh, xt);
    proj_kernel<<<dim3(896), dim3(256), 0, stream>>>(xt, Wh, b2, QKt);
    sim_kernel<<<dim3(3136), dim3(256), 0, stream>>>(QKt, S);
    norm_kernel<<<dim3((N_ + 3) / 4, B_), dim3(256), 0, stream>>>(fg, bg, S);
    ctx_kernel<<<dim3(896), dim3(256), 0, stream>>>(xh, S, x, gamma, out);
}

// Round 3
// 626.178 us; speedup vs baseline: 1.0744x; 1.0744x over previous
//
#include <hip/hip_runtime.h>
#include <math.h>

#define B_   16
#define C_   512
#define N_   1681
#define Np   1792      // padded N (multiple of 128)
#define CK_  256
#define EPSV 1e-5f
#define SCALE 0.0625f  // Ck^-0.5

#define SLOT_BYTES 32768   // one ring slot: A half 16KB + B half 16KB
#define LDS_BYTES  131072  // 4 slots

typedef __bf16 bf16x8 __attribute__((ext_vector_type(8)));
typedef __bf16 bf16x4 __attribute__((ext_vector_type(4)));
typedef float  f32x4  __attribute__((ext_vector_type(4)));

// ---------------------------------------------------------------------------
// XCD-aware bijective swizzle (nwg % 8 == 0): q = nwg/8.
// ---------------------------------------------------------------------------
__device__ __forceinline__ int xcd_swz(int orig, int q)
{
    return (orig & 7) * q + (orig >> 3);
}

// ---------------------------------------------------------------------------
// Stage one 256-row x 32-bf16 (64 B/row) panel global->LDS.
// 16 KB = 1024 chunks of 16B; 512 threads x 2 gll (wave-uniform base +
// lane*16 linear dest; inverse-swizzled global source: chunk ^= (row>>1)&3).
// ---------------------------------------------------------------------------
__device__ __forceinline__
void stage_half(const char* g, int ld_bytes, char* l, int tid)
{
    #pragma unroll
    for (int r = 0; r < 2; ++r) {
        int chunk = r * 512 + tid;            // 0..1023
        int row   = chunk >> 2;               // 4 chunks (64B) per row
        int col   = chunk & 3;
        int scol  = col ^ ((row >> 1) & 3);
        __builtin_amdgcn_global_load_lds(
            (const __attribute__((address_space(1))) void*)(g + (size_t)row * ld_bytes + scol * 16),
            (__attribute__((address_space(3))) void*)(l + (size_t)chunk * 16), 16, 0, 0);
    }
}

__device__ __forceinline__
bf16x8 lds_frag(const __bf16* base, int row, int quad)
{
    int c = quad ^ ((row >> 1) & 3);
    return *(const bf16x8*)(base + (size_t)row * 32 + c * 8);
}

// ---------------------------------------------------------------------------
// 256x256-tile GEMM core, BK=32, 8 waves (2M x 4N), 4-slot LDS ring,
// lead-2 prefetch, counted vmcnt(4) at tile boundaries (never 0 in steady
// state).  acc[8][4]: wave output 128 rows x 64 cols of C.
// ---------------------------------------------------------------------------
__device__ __forceinline__
void gemm_core(const char* __restrict__ Ab, int lda,
               const char* __restrict__ Bb, int ldb,
               char* slots, f32x4 acc[8][4], int nt)
{
    const int tid = threadIdx.x;
    const int wid = tid >> 6, lane = tid & 63;
    const int wm = wid >> 2, wn = wid & 3;
    const int l15 = lane & 15, quad = lane >> 4;

    // prologue: stage tiles 0 and 1 (k-offset = t*32 elems = t*64 bytes)
    stage_half(Ab,      lda, slots,                           tid);
    stage_half(Bb,      ldb, slots + 16384,                   tid);
    stage_half(Ab + 64, lda, slots + SLOT_BYTES,              tid);
    stage_half(Bb + 64, ldb, slots + SLOT_BYTES + 16384,      tid);
    asm volatile("s_waitcnt vmcnt(4)" ::: "memory");   // tile0 landed; tile1 in flight
    __builtin_amdgcn_s_barrier();

    for (int t = 0; t < nt; ++t) {
        const __bf16* As = (const __bf16*)(slots + (size_t)(t & 3) * SLOT_BYTES);
        const __bf16* Bs = (const __bf16*)(slots + (size_t)(t & 3) * SLOT_BYTES + 16384);
        char* dst = slots + (size_t)((t + 2) & 3) * SLOT_BYTES;
        const bool more = (t + 2) < nt;

        bf16x8 af[4], bfr[4];
        // ---- phase 0: C-half mf 0-3 (full BK=32) ----
        #pragma unroll
        for (int i = 0; i < 4; ++i)
            af[i] = lds_frag(As, wm * 128 + i * 16 + l15, quad);
        #pragma unroll
        for (int j = 0; j < 4; ++j)
            bfr[j] = lds_frag(Bs, wn * 64 + j * 16 + l15, quad);
        if (more) stage_half(Ab + (size_t)(t + 2) * 64, lda, dst, tid);
        __builtin_amdgcn_s_setprio(1);
        #pragma unroll
        for (int i = 0; i < 4; ++i)
            #pragma unroll
            for (int j = 0; j < 4; ++j)
                acc[i][j] = __builtin_amdgcn_mfma_f32_16x16x32_bf16(
                    af[i], bfr[j], acc[i][j], 0, 0, 0);
        __builtin_amdgcn_s_setprio(0);
        __builtin_amdgcn_s_barrier();

        // ---- phase 1: C-half mf 4-7 (B frags reused from registers) ----
        #pragma unroll
        for (int i = 0; i < 4; ++i)
            af[i] = lds_frag(As, wm * 128 + (4 + i) * 16 + l15, quad);
        if (more) stage_half(Bb + (size_t)(t + 2) * 64, ldb, dst + 16384, tid);
        __builtin_amdgcn_s_setprio(1);
        #pragma unroll
        for (int i = 0; i < 4; ++i)
            #pragma unroll
            for (int j = 0; j < 4; ++j)
                acc[4 + i][j] = __builtin_amdgcn_mfma_f32_16x16x32_bf16(
                    af[i], bfr[j], acc[4 + i][j], 0, 0, 0);
        __builtin_amdgcn_s_setprio(0);

        // ---- tile boundary: drain tile t+1's 4 loads, keep t+2's in flight ----
        if (more) asm volatile("s_waitcnt vmcnt(4)" ::: "memory");
        else      asm volatile("s_waitcnt vmcnt(0)" ::: "memory");
        __builtin_amdgcn_s_barrier();
    }
}

// ---------------------------------------------------------------------------
// cvt_w: Wh[512][512] bf16 = [Wq; Wk], b2[512] f32 = [bq; bk]
// ---------------------------------------------------------------------------
__global__ __launch_bounds__(256)
void cvt_w_kernel(const float* __restrict__ Wq, const float* __restrict__ Wk,
                  const float* __restrict__ bq, const float* __restrict__ bk,
                  __bf16* __restrict__ Wh, float* __restrict__ b2)
{
    int idx = blockIdx.x * 1024 + threadIdx.x * 4;
    #pragma unroll
    for (int p = 0; p < 4; ++p) {
        int e = idx + p;
        int row = e >> 9, col = e & 511;
        float v = (row < 256) ? Wq[row * 512 + col] : Wk[(row - 256) * 512 + col];
        Wh[e] = (__bf16)v;
    }
    if (blockIdx.x == 0) {
        int t = threadIdx.x;
        b2[t]       = bq[t];
        b2[256 + t] = bk[t];
    }
}

// ---------------------------------------------------------------------------
// cvt_x: xh[b][c][n<Np] bf16 (zero pad), xt[b][n<Np][c] bf16 (zero pad rows)
// ---------------------------------------------------------------------------
__global__ __launch_bounds__(256)
void cvt_x_kernel(const float* __restrict__ x,
                  __bf16* __restrict__ xh, __bf16* __restrict__ xt)
{
    __shared__ float tile[32][33];
    const int t = threadIdx.x;
    const int n0 = blockIdx.x * 32, c0 = blockIdx.y * 32, b = blockIdx.z;
    const float* xb = x + (size_t)b * C_ * N_;
    #pragma unroll
    for (int p = 0; p < 4; ++p) {
        int lin = p * 256 + t;
        int i = lin >> 5, j = lin & 31;
        int n = n0 + j;
        float v = (n < N_) ? xb[(size_t)(c0 + i) * N_ + n] : 0.0f;
        tile[i][j] = v;
        xh[(size_t)b * C_ * Np + (size_t)(c0 + i) * Np + n] = (__bf16)v;
    }
    __syncthreads();
    #pragma unroll
    for (int p = 0; p < 4; ++p) {
        int lin = p * 256 + t;
        int i = lin >> 5, j = lin & 31;
        xt[(size_t)b * Np * C_ + (size_t)(n0 + i) * C_ + (c0 + j)] = (__bf16)tile[j][i];
    }
}

// ---------------------------------------------------------------------------
// proj: QKt[b][n][k2] = sum_c xt[b][n][c] * Wh[k2][c] + b2[k2]
// 224 blocks: (k2-tile 2) fastest, (n-tile 7), b 16.
// ---------------------------------------------------------------------------
__global__ __launch_bounds__(512, 2)
void proj_kernel(const __bf16* __restrict__ xt, const __bf16* __restrict__ Wh,
                 const float* __restrict__ b2, __bf16* __restrict__ QKt)
{
    extern __shared__ char slots[];
    const int wg = xcd_swz(blockIdx.x, 28);        // 224/8
    const int k20 = (wg & 1) * 256;
    const int n0  = ((wg >> 1) % 7) * 256;
    const int b   = wg / 14;
    const char* Abase = (const char*)xt + ((size_t)b * Np + n0) * (C_ * 2);
    const char* Bbase = (const char*)Wh + (size_t)k20 * (C_ * 2);

    f32x4 acc[8][4] = {};
    gemm_core(Abase, C_ * 2, Bbase, C_ * 2, slots, acc, C_ / 32);

    const int tid = threadIdx.x, wid = tid >> 6, lane = tid & 63;
    const int wm = wid >> 2, wn = wid & 3;
    const int l15 = lane & 15, quad = lane >> 4;
    __bf16* ob = QKt + (size_t)b * Np * 512;
    #pragma unroll
    for (int j = 0; j < 4; ++j) {
        int k2 = k20 + wn * 64 + j * 16 + l15;
        float bias = b2[k2];
        #pragma unroll
        for (int i = 0; i < 8; ++i)
            #pragma unroll
            for (int r = 0; r < 4; ++r) {
                int n = n0 + wm * 128 + i * 16 + quad * 4 + r;
                ob[(size_t)n * 512 + k2] = (__bf16)(acc[i][j][r] + bias);
            }
    }
}

// ---------------------------------------------------------------------------
// sim: S[b][n][m] = SCALE * sum_k Qt[n][k] * Kt[m][k]
// 784 blocks: (m-tile 7) fastest, (n-tile 7), b 16.
// ---------------------------------------------------------------------------
__global__ __launch_bounds__(512, 2)
void sim_kernel(const __bf16* __restrict__ QKt, __bf16* __restrict__ S)
{
    extern __shared__ char slots[];
    const int wg = xcd_swz(blockIdx.x, 98);        // 784/8
    const int m0 = (wg % 7) * 256;
    const int n0 = ((wg / 7) % 7) * 256;
    const int b  = wg / 49;
    const char* base = (const char*)QKt + (size_t)b * Np * 1024;
    const char* Abase = base + (size_t)n0 * 1024;          // Qt rows
    const char* Bbase = base + (size_t)m0 * 1024 + 512;    // Kt rows (+256 elems)

    f32x4 acc[8][4] = {};
    gemm_core(Abase, 1024, Bbase, 1024, slots, acc, CK_ / 32);

    const int tid = threadIdx.x, wid = tid >> 6, lane = tid & 63;
    const int wm = wid >> 2, wn = wid & 3;
    const int l15 = lane & 15, quad = lane >> 4;
    __bf16* Sb = S + (size_t)b * Np * Np;
    #pragma unroll
    for (int i = 0; i < 8; ++i)
        #pragma unroll
        for (int r = 0; r < 4; ++r) {
            int n = n0 + wm * 128 + i * 16 + quad * 4 + r;
            #pragma unroll
            for (int j = 0; j < 4; ++j) {
                int m = m0 + wn * 64 + j * 16 + l15;
                Sb[(size_t)n * Np + m] = (__bf16)(acc[i][j][r] * SCALE);
            }
        }
}

// ---------------------------------------------------------------------------
// norm: one WAVE per row, register-resident, vectorized, no LDS/barriers.
// Single sweep: min(s*f), A=sum(s*f^2), F=sum(f); sum_x1 = A - min*F.
// ---------------------------------------------------------------------------
__global__ __launch_bounds__(256, 4)
void norm_kernel(const float* __restrict__ fg, const float* __restrict__ bg,
                 __bf16* __restrict__ S)
{
    const int t = threadIdx.x;
    const int wid = t >> 6, lane = t & 63;
    const int n = blockIdx.x * 4 + wid;
    const int b = blockIdx.y;
    if (n >= N_) return;

    __bf16* Srow = S + (size_t)b * Np * Np + (size_t)n * Np;
    const float* fgrow = fg + ((size_t)b * N_ + n) * N_;
    const float* bgrow = bg + ((size_t)b * N_ + n) * N_;

    float sv[7][4];
    float fv[7][4];
    float lmin = INFINITY, aSum = 0.0f, fSum = 0.0f;

    #pragma unroll
    for (int i = 0; i < 7; ++i) {
        const int m0 = i * 256 + lane * 4;
        bf16x4 sr = *(const bf16x4*)(Srow + m0);
        f32x4 f;
        if (m0 + 4 <= N_) {
            f = *(const f32x4*)(fgrow + m0);
        } else {
            f[0] = (m0 + 0 < N_) ? fgrow[m0 + 0] : 0.0f;
            f[1] = (m0 + 1 < N_) ? fgrow[m0 + 1] : 0.0f;
            f[2] = (m0 + 2 < N_) ? fgrow[m0 + 2] : 0.0f;
            f[3] = (m0 + 3 < N_) ? fgrow[m0 + 3] : 0.0f;
        }
        #pragma unroll
        for (int k = 0; k < 4; ++k) {
            const bool valid = (m0 + k) < N_;
            const float fk = f[k];
            const float svk = (float)sr[k] * fk;
            sv[i][k] = svk;
            fv[i][k] = fk;
            aSum += svk * fk;
            fSum += fk;
            lmin = fminf(lmin, valid ? svk : INFINITY);
        }
    }

    #pragma unroll
    for (int off = 1; off < 64; off <<= 1) {
        lmin = fminf(lmin, __shfl_xor(lmin, off, 64));
        aSum += __shfl_xor(aSum, off, 64);
        fSum += __shfl_xor(fSum, off, 64);
    }
    const float inv = 1.0f / ((aSum - lmin * fSum) + EPSV);

    #pragma unroll
    for (int i = 0; i < 7; ++i) {
        const int m0 = i * 256 + lane * 4;
        f32x4 g;
        if (m0 + 4 <= N_) {
            g = *(const f32x4*)(bgrow + m0);
        } else {
            g[0] = (m0 + 0 < N_) ? bgrow[m0 + 0] : 0.0f;
            g[1] = (m0 + 1 < N_) ? bgrow[m0 + 1] : 0.0f;
            g[2] = (m0 + 2 < N_) ? bgrow[m0 + 2] : 0.0f;
            g[3] = (m0 + 3 < N_) ? bgrow[m0 + 3] : 0.0f;
        }
        bf16x4 o;
        #pragma unroll
        for (int k = 0; k < 4; ++k) {
            const bool valid = (m0 + k) < N_;
            const float x1 = (sv[i][k] - lmin) * fv[i][k];
            o[k] = (__bf16)(valid ? (x1 * inv + g[k]) : 0.0f);
        }
        *(bf16x4*)(Srow + m0) = o;
    }
}

// ---------------------------------------------------------------------------
// ctx: out[b][c][n] = gamma * sum_m xh[c][m] * A'[n][m] + x[b][c][n]
// 224 blocks: (c-tile 2) fastest, (n-tile 7), b 16.
// ---------------------------------------------------------------------------
__global__ __launch_bounds__(512, 2)
void ctx_kernel(const __bf16* __restrict__ xh, const __bf16* __restrict__ Ap,
                const float* __restrict__ x, const float* __restrict__ gamma,
                float* __restrict__ out)
{
    extern __shared__ char slots[];
    const int wg = xcd_swz(blockIdx.x, 28);        // 224/8
    const int c0 = (wg & 1) * 256;
    const int n0 = ((wg >> 1) % 7) * 256;
    const int b  = wg / 14;
    const char* Abase = (const char*)xh + ((size_t)b * C_ + c0) * (Np * 2);
    const char* Bbase = (const char*)Ap + ((size_t)b * Np + n0) * (Np * 2);

    f32x4 acc[8][4] = {};
    gemm_core(Abase, Np * 2, Bbase, Np * 2, slots, acc, Np / 32);

    const int tid = threadIdx.x, wid = tid >> 6, lane = tid & 63;
    const int wm = wid >> 2, wn = wid & 3;
    const int l15 = lane & 15, quad = lane >> 4;
    const float g = gamma[0];
    const float* xb = x + (size_t)b * C_ * N_;
    float* ob = out + (size_t)b * C_ * N_;
    #pragma unroll
    for (int i = 0; i < 8; ++i)
        #pragma unroll
        for (int r = 0; r < 4; ++r) {
            int c = c0 + wm * 128 + i * 16 + quad * 4 + r;
            #pragma unroll
            for (int j = 0; j < 4; ++j) {
                int n = n0 + wn * 64 + j * 16 + l15;
                if (n < N_) {
                    size_t idx = (size_t)c * N_ + n;
                    ob[idx] = g * acc[i][j][r] + xb[idx];
                }
            }
        }
}

// ---------------------------------------------------------------------------
extern "C" void kernel_launch(void* const* d_in, const int* in_sizes, int n_in,
                              void* d_out, int out_size, void* d_ws, size_t ws_size,
                              hipStream_t stream)
{
    const float* x     = (const float*)d_in[0];
    const float* fg    = (const float*)d_in[1];
    const float* bg    = (const float*)d_in[2];
    const float* Wq    = (const float*)d_in[3];
    const float* bq    = (const float*)d_in[4];
    const float* Wk    = (const float*)d_in[5];
    const float* bk    = (const float*)d_in[6];
    const float* gamma = (const float*)d_in[7];
    float* out = (float*)d_out;

    char* p = (char*)d_ws;
    __bf16* xh  = (__bf16*)p; p += (size_t)B_ * C_ * Np * 2;   // 29.4 MB
    __bf16* xt  = (__bf16*)p; p += (size_t)B_ * Np * C_ * 2;   // 29.4 MB
    __bf16* QKt = (__bf16*)p; p += (size_t)B_ * Np * 512 * 2;  // 29.4 MB
    __bf16* S   = (__bf16*)p; p += (size_t)B_ * Np * Np * 2;   // 102.8 MB
    __bf16* Wh  = (__bf16*)p; p += (size_t)512 * 512 * 2;      // 0.5 MB
    float*  b2  = (float*)p;                                   // 2 KB

    static bool attr_done = false;
    if (!attr_done) {
        hipFuncSetAttribute((const void*)proj_kernel,
                            hipFuncAttributeMaxDynamicSharedMemorySize, LDS_BYTES);
        hipFuncSetAttribute((const void*)sim_kernel,
                            hipFuncAttributeMaxDynamicSharedMemorySize, LDS_BYTES);
        hipFuncSetAttribute((const void*)ctx_kernel,
                            hipFuncAttributeMaxDynamicSharedMemorySize, LDS_BYTES);
        attr_done = true;
    }

    cvt_w_kernel<<<dim3(256), dim3(256), 0, stream>>>(Wq, Wk, bq, bk, Wh, b2);
    cvt_x_kernel<<<dim3(Np / 32, C_ / 32, B_), dim3(256), 0, stream>>>(x, xh, xt);
    proj_kernel<<<dim3(224), dim3(512), LDS_BYTES, stream>>>(xt, Wh, b2, QKt);
    sim_kernel<<<dim3(784), dim3(512), LDS_BYTES, stream>>>(QKt, S);
    norm_kernel<<<dim3((N_ + 3) / 4, B_), dim3(256), 0, stream>>>(fg, bg, S);
    ctx_kernel<<<dim3(224), dim3(512), LDS_BYTES, stream>>>(xh, S, x, gamma, out);
}